// Round 2
// baseline (576.674 us; speedup 1.0000x reference)
//
#include <hip/hip_runtime.h>
#include <cstdint>
#include <cstddef>

#define NB 512
#define N_PER 2048
#define NC 64
#define DEG 16
#define KSEL 1024
#define NTOT (NB * N_PER)        // 1048576 nodes
#define ETOT (NTOT * DEG)        // 16777216 edges
#define NOUT (NB * KSEL)         // 524288 kept nodes

#define T 1024                   // threads per block (16 waves)
#define EPT 2                    // sort elements per thread (N_PER / T)

// d_out layout (float32; int values < 2^24 exact):
//   [0)          x_out      NOUT*NC  = 33554432
//   [33554432)   new_edge   2*ETOT   = 33554432
//   [67108864)   new_batch  NOUT
//   [67633152)   perm       NOUT
//   [68157440)   score      NOUT

// One block per graph, 1024 threads -> 2 blocks/CU * 16 waves = 32 waves/CU.
// Phases:
//  1) f64 dot per node (tanh monotone -> sort raw dot; tanh only for kept)
//  2) bitonic sort of 2048 keys, 2/thread: register (j=1) + shfl (j=2..64) +
//     LDS stages (j=128..1024, slot-major, conflict-free)
//  3) outputs + LDS node map
//  4) gather x_out (per-graph local)
//  5) edge remap through LDS lmap (per-graph local)
__global__ __launch_bounds__(T, 8) void fused_topk_kernel(
    const float* __restrict__ x, const float* __restrict__ p,
    const int* __restrict__ ei,
    float* __restrict__ out_x, float* __restrict__ out_edge,
    float* __restrict__ out_batch, float* __restrict__ out_perm,
    float* __restrict__ out_score) {
  __shared__ unsigned long long key2[EPT][T];  // 16 KB, slot-major
  __shared__ int lmap[N_PER];                  // 8 KB
  __shared__ int klist[KSEL];                  // 4 KB
  __shared__ float kscore[KSEL];               // 4 KB
  __shared__ double p_s[NC];
  __shared__ double norm_s;

  const int tid = threadIdx.x;
  const int b = blockIdx.x;
  const int base = b * N_PER;

  if (tid < NC) p_s[tid] = (double)p[tid];
  __syncthreads();
  if (tid == 0) {
    double s = 0.0;
    for (int i = 0; i < NC; ++i) s += p_s[i] * p_s[i];
    norm_s = sqrt(s);
  }

  // ---- Phase 1: f64 dot -> packed sort key, slot-major into key2 ----
  // 16 lanes per row (float4 each = 64 channels); 64 rows per pass.
  const int lane = tid & 15;
  const int rowg = tid >> 4;  // 0..63
  const double pw0 = p_s[lane * 4 + 0];
  const double pw1 = p_s[lane * 4 + 1];
  const double pw2 = p_s[lane * 4 + 2];
  const double pw3 = p_s[lane * 4 + 3];
  const float4* xrow = (const float4*)(x + (size_t)base * NC);

  for (int r0 = 0; r0 < N_PER; r0 += 64) {
    const int row = r0 + rowg;
    float4 v = xrow[row * 16 + lane];
    double part = (double)v.x * pw0 + (double)v.y * pw1 +
                  (double)v.z * pw2 + (double)v.w * pw3;
    part += __shfl_xor(part, 8, 16);
    part += __shfl_xor(part, 4, 16);
    part += __shfl_xor(part, 2, 16);
    part += __shfl_xor(part, 1, 16);
    if (lane == 0) {
      // ascending-sort order == descending dot, tie -> lower idx.
      unsigned long long u = (unsigned long long)__double_as_longlong(part);
      unsigned long long asc =
          (u & 0x8000000000000000ULL) ? ~u : (u | 0x8000000000000000ULL);
      unsigned long long desc = ~asc;
      key2[row & 1][row >> 1] = (desc & ~2047ULL) | (unsigned long long)row;
    }
  }
  __syncthreads();

  // ---- Phase 2: bitonic sort, 2 keys/thread (element e = tid*2 + s) ----
  unsigned long long r0k = key2[0][tid];
  unsigned long long r1k = key2[1][tid];

  auto CE = [](unsigned long long& a, unsigned long long& c, bool up) {
    if ((a > c) == up) { unsigned long long t = a; a = c; c = t; }
  };
  auto shfl_stage = [&](int m, bool up) {
    // partner element e^j, j = 2m -> thread tid^m, same slot
    const bool keepmin = (((tid & m) == 0) == up);
    unsigned long long o0 = __shfl_xor(r0k, m, 64);
    unsigned long long o1 = __shfl_xor(r1k, m, 64);
    if (keepmin ? (o0 < r0k) : (o0 > r0k)) r0k = o0;
    if (keepmin ? (o1 < r1k) : (o1 > r1k)) r1k = o1;
  };
  auto lds_stage = [&](int m, bool up) {
    __syncthreads();
    key2[0][tid] = r0k;
    key2[1][tid] = r1k;
    __syncthreads();
    const bool keepmin = (((tid & m) == 0) == up);
    unsigned long long o0 = key2[0][tid ^ m];
    unsigned long long o1 = key2[1][tid ^ m];
    if (keepmin ? (o0 < r0k) : (o0 > r0k)) r0k = o0;
    if (keepmin ? (o1 < r1k) : (o1 > r1k)) r1k = o1;
  };

  // k = 2: pair (2t, 2t+1), direction from e&2 = (tid&1)<<1
  CE(r0k, r1k, (tid & 1) == 0);
  // k = 4 .. 2048: direction up = ((e & k) == 0) = ((tid & (k>>1)) == 0)
#pragma unroll
  for (int k = 4; k <= N_PER; k <<= 1) {
    const bool up = ((tid & (k >> 1)) == 0);
#pragma unroll
    for (int j = (k >> 1); j >= 128; j >>= 1) lds_stage(j >> 1, up);  // cross-wave
#pragma unroll
    for (int j = ((k >> 1) > 64 ? 64 : (k >> 1)); j >= 2; j >>= 1)
      shfl_stage(j >> 1, up);                                          // intra-wave
    CE(r0k, r1k, up);                                                  // j = 1
  }

  // ---- Phase 3: outputs + LDS node map ----
  __syncthreads();
  const double norm = norm_s;
#pragma unroll
  for (int s = 0; s < EPT; ++s) {
    const unsigned long long key = (s == 0) ? r0k : r1k;
    const int pos = tid * EPT + s;
    const int idx = (int)(key & 2047ULL);
    if (pos < KSEL) {
      // recover dot from key (low 11 mantissa bits lost: rel err ~2^-41)
      unsigned long long desc = key & ~2047ULL;
      unsigned long long asc = ~desc;
      unsigned long long u = (asc & 0x8000000000000000ULL)
                                 ? (asc ^ 0x8000000000000000ULL)
                                 : ~asc;
      const double dot = __longlong_as_double((long long)u);
      const float sc = tanhf((float)(dot / norm));
      const int nid = b * KSEL + pos;
      out_batch[nid] = (float)b;
      out_perm[nid] = (float)(base + idx);
      out_score[nid] = sc;
      klist[pos] = idx;
      kscore[pos] = sc;
      lmap[idx] = nid;
    } else {
      lmap[idx] = -1;
    }
  }
  __syncthreads();

  // ---- Phase 4: gather x_out = x[perm] * score (64 rows / iter) ----
  const float4* xg = (const float4*)x;
  float4* xo = (float4*)out_x;
#pragma unroll 4
  for (int rr = 0; rr < KSEL; rr += 64) {
    const int row = rr + rowg;
    const int idx = klist[row];
    const float sc = kscore[row];
    float4 v = xg[(size_t)(base + idx) * 16 + lane];
    v.x *= sc; v.y *= sc; v.z *= sc; v.w *= sc;
    xo[(size_t)(b * KSEL + row) * 16 + lane] = v;
  }

  // ---- Phase 5: edge remap through LDS lmap ----
  const int nE4 = N_PER * DEG / 4;  // 8192 int4 per row of edge_index
  const int4* s_ei = (const int4*)ei + (size_t)b * nE4;
  const int4* d_ei = (const int4*)(ei + (size_t)ETOT) + (size_t)b * nE4;
  float4* o_s = (float4*)out_edge + (size_t)b * nE4;
  float4* o_d = (float4*)(out_edge + (size_t)ETOT) + (size_t)b * nE4;
#pragma unroll 2
  for (int i = tid; i < nE4; i += T) {
    const int4 s4 = s_ei[i];
    const int4 d4 = d_ei[i];
    const int ns0 = lmap[s4.x - base], ns1 = lmap[s4.y - base];
    const int ns2 = lmap[s4.z - base], ns3 = lmap[s4.w - base];
    const int nd0 = lmap[d4.x - base], nd1 = lmap[d4.y - base];
    const int nd2 = lmap[d4.z - base], nd3 = lmap[d4.w - base];
    float4 os, od;
    const bool k0 = (ns0 >= 0) && (nd0 >= 0);
    const bool k1 = (ns1 >= 0) && (nd1 >= 0);
    const bool k2 = (ns2 >= 0) && (nd2 >= 0);
    const bool k3 = (ns3 >= 0) && (nd3 >= 0);
    os.x = k0 ? (float)ns0 : -1.0f; od.x = k0 ? (float)nd0 : -1.0f;
    os.y = k1 ? (float)ns1 : -1.0f; od.y = k1 ? (float)nd1 : -1.0f;
    os.z = k2 ? (float)ns2 : -1.0f; od.z = k2 ? (float)nd2 : -1.0f;
    os.w = k3 ? (float)ns3 : -1.0f; od.w = k3 ? (float)nd3 : -1.0f;
    o_s[i] = os;
    o_d[i] = od;
  }
}

extern "C" void kernel_launch(void* const* d_in, const int* in_sizes, int n_in,
                              void* d_out, int out_size, void* d_ws,
                              size_t ws_size, hipStream_t stream) {
  const float* x = (const float*)d_in[0];
  const int* ei = (const int*)d_in[1];
  // d_in[2] = batch (implied by construction; unused)
  const float* p = (const float*)d_in[3];

  float* out = (float*)d_out;
  float* out_x = out;                // 33554432
  float* out_edge = out + 33554432;  // 33554432
  float* out_batch = out + 67108864;
  float* out_perm = out + 67633152;
  float* out_score = out + 68157440;

  fused_topk_kernel<<<NB, T, 0, stream>>>(x, p, ei, out_x, out_edge, out_batch,
                                          out_perm, out_score);
}

// Round 3
// 574.252 us; speedup vs baseline: 1.0042x; 1.0042x over previous
//
#include <hip/hip_runtime.h>
#include <cstdint>
#include <cstddef>

#define NB 512
#define N_PER 2048
#define NC 64
#define DEG 16
#define KSEL 1024
#define NTOT (NB * N_PER)        // 1048576 nodes
#define ETOT (NTOT * DEG)        // 16777216 edges
#define NOUT (NB * KSEL)         // 524288 kept nodes

#define T 1024                   // threads per block (16 waves)
#define EPT 2                    // sort elements per thread (N_PER / T)

// d_out layout (float32; int values < 2^24 exact):
//   [0)          x_out      NOUT*NC  = 33554432
//   [33554432)   new_edge   2*ETOT   = 33554432
//   [67108864)   new_batch  NOUT
//   [67633152)   perm       NOUT
//   [68157440)   score      NOUT

// One block per graph, 1024 threads. Sort: bitonic 2048 @ 2 keys/thread.
//  - cross-wave stages (j>=128) pair (j, j/2) into ONE LDS round-trip:
//      post_j[e]        = sel(pre[e],        pre[e^j],        km_j)
//      post_j[e^(j/2)]  = sel(pre[e^(j/2)],  pre[e^(j/2)^j],  km_j)   (same km)
//      final[e]         = sel(post_j[e], post_j[e^(j/2)], km_{j/2})
//    -> 6 LDS rounds / 12 barriers (was 10 / 20).
//  - final level (k=2048, up=true): after j=1024, lower 1024 positions hold the
//    kept set (bitonic); upper half needs membership only -> waves 8..15 stop.
__global__ __launch_bounds__(T, 8) void fused_topk_kernel(
    const float* __restrict__ x, const float* __restrict__ p,
    const int* __restrict__ ei,
    float* __restrict__ out_x, float* __restrict__ out_edge,
    float* __restrict__ out_batch, float* __restrict__ out_perm,
    float* __restrict__ out_score) {
  __shared__ unsigned long long key2[EPT][T];  // 16 KB, slot-major
  __shared__ int lmap[N_PER];                  // 8 KB
  __shared__ int klist[KSEL];                  // 4 KB
  __shared__ float kscore[KSEL];               // 4 KB
  __shared__ double p_s[NC];
  __shared__ double norm_s;

  const int tid = threadIdx.x;
  const int b = blockIdx.x;
  const int base = b * N_PER;

  if (tid < NC) p_s[tid] = (double)p[tid];
  __syncthreads();
  if (tid == 0) {
    double s = 0.0;
    for (int i = 0; i < NC; ++i) s += p_s[i] * p_s[i];
    norm_s = sqrt(s);
  }

  // ---- Phase 1: f64 dot -> packed sort key, slot-major into key2 ----
  const int lane = tid & 15;
  const int rowg = tid >> 4;  // 0..63
  const double pw0 = p_s[lane * 4 + 0];
  const double pw1 = p_s[lane * 4 + 1];
  const double pw2 = p_s[lane * 4 + 2];
  const double pw3 = p_s[lane * 4 + 3];
  const float4* xrow = (const float4*)(x + (size_t)base * NC);

  for (int r0 = 0; r0 < N_PER; r0 += 64) {
    const int row = r0 + rowg;
    float4 v = xrow[row * 16 + lane];
    double part = (double)v.x * pw0 + (double)v.y * pw1 +
                  (double)v.z * pw2 + (double)v.w * pw3;
    part += __shfl_xor(part, 8, 16);
    part += __shfl_xor(part, 4, 16);
    part += __shfl_xor(part, 2, 16);
    part += __shfl_xor(part, 1, 16);
    if (lane == 0) {
      // ascending-sort order == descending dot, tie -> lower idx.
      unsigned long long u = (unsigned long long)__double_as_longlong(part);
      unsigned long long asc =
          (u & 0x8000000000000000ULL) ? ~u : (u | 0x8000000000000000ULL);
      unsigned long long desc = ~asc;
      key2[row & 1][row >> 1] = (desc & ~2047ULL) | (unsigned long long)row;
    }
  }
  __syncthreads();

  // ---- Phase 2: bitonic sort, 2 keys/thread (element e = tid*2 + s) ----
  unsigned long long r0k = key2[0][tid];
  unsigned long long r1k = key2[1][tid];

  auto SEL = [](unsigned long long a, unsigned long long c, bool keepmin) {
    return keepmin ? (a < c ? a : c) : (a > c ? a : c);
  };
  auto CE = [](unsigned long long& a, unsigned long long& c, bool up) {
    if ((a > c) == up) { unsigned long long t = a; a = c; c = t; }
  };
  auto shfl_stage = [&](int m, bool up) {
    const bool km = (((tid & m) == 0) == up);
    unsigned long long o0 = __shfl_xor(r0k, m, 64);
    unsigned long long o1 = __shfl_xor(r1k, m, 64);
    r0k = SEL(r0k, o0, km);
    r1k = SEL(r1k, o1, km);
  };
  auto shfl_tail = [&](bool up) {  // j = 64..2 then j = 1
    shfl_stage(32, up); shfl_stage(16, up); shfl_stage(8, up);
    shfl_stage(4, up);  shfl_stage(2, up);  shfl_stage(1, up);
    CE(r0k, r1k, up);
  };
  auto lds_single = [&](int m, bool up) {
    __syncthreads();
    key2[0][tid] = r0k; key2[1][tid] = r1k;
    __syncthreads();
    const bool km = (((tid & m) == 0) == up);
    r0k = SEL(r0k, key2[0][tid ^ m], km);
    r1k = SEL(r1k, key2[1][tid ^ m], km);
  };
  auto lds_pair = [&](int m, int m2, bool up) {  // stages j=2m then j=2m2
    __syncthreads();
    key2[0][tid] = r0k; key2[1][tid] = r1k;
    __syncthreads();
    const bool kmJ = (((tid & m) == 0) == up);
    const bool kmJ2 = (((tid & m2) == 0) == up);
    {
      unsigned long long pj = key2[0][tid ^ m];
      unsigned long long pj2 = key2[0][tid ^ m2];
      unsigned long long pjj = key2[0][tid ^ m ^ m2];
      r0k = SEL(SEL(r0k, pj, kmJ), SEL(pj2, pjj, kmJ), kmJ2);
    }
    {
      unsigned long long pj = key2[1][tid ^ m];
      unsigned long long pj2 = key2[1][tid ^ m2];
      unsigned long long pjj = key2[1][tid ^ m ^ m2];
      r1k = SEL(SEL(r1k, pj, kmJ), SEL(pj2, pjj, kmJ), kmJ2);
    }
  };

  // k = 2
  CE(r0k, r1k, (tid & 1) == 0);
  // k = 4..128: pure shfl levels
#pragma unroll
  for (int k = 4; k <= 128; k <<= 1) {
    const bool up = ((tid & (k >> 1)) == 0);
#pragma unroll
    for (int j = (k >> 1); j >= 2; j >>= 1) shfl_stage(j >> 1, up);
    CE(r0k, r1k, up);
  }
  // k = 256: LDS j=128
  {
    const bool up = ((tid & 128) == 0);
    lds_single(64, up);
    shfl_tail(up);
  }
  // k = 512: LDS j=256,128
  {
    const bool up = ((tid & 256) == 0);
    lds_pair(128, 64, up);
    shfl_tail(up);
  }
  // k = 1024: LDS j=512,256,128
  {
    const bool up = ((tid & 512) == 0);
    lds_pair(256, 128, up);
    lds_single(64, up);
    shfl_tail(up);
  }
  // k = 2048 (up = true for all): pairA j=1024,512 (all), then lower half only
  __syncthreads();
  key2[0][tid] = r0k; key2[1][tid] = r1k;
  __syncthreads();
  if (tid < 512) {
    const bool kmJ2 = ((tid & 256) == 0);
    {
      unsigned long long pj = key2[0][tid ^ 512];
      unsigned long long pj2 = key2[0][tid ^ 256];
      unsigned long long pjj = key2[0][tid ^ 768];
      r0k = SEL(SEL(r0k, pj, true), SEL(pj2, pjj, true), kmJ2);
    }
    {
      unsigned long long pj = key2[1][tid ^ 512];
      unsigned long long pj2 = key2[1][tid ^ 256];
      unsigned long long pjj = key2[1][tid ^ 768];
      r1k = SEL(SEL(r1k, pj, true), SEL(pj2, pjj, true), kmJ2);
    }
  } else {
    // upper half: only j=1024 (keepmax); order within upper half irrelevant
    r0k = SEL(r0k, key2[0][tid ^ 512], false);
    r1k = SEL(r1k, key2[1][tid ^ 512], false);
  }
  // pairB j=256,128 + tail: lower half only (upper just hits barriers)
  __syncthreads();
  if (tid < 512) { key2[0][tid] = r0k; key2[1][tid] = r1k; }
  __syncthreads();
  if (tid < 512) {
    const bool kmJ = ((tid & 128) == 0);
    const bool kmJ2 = ((tid & 64) == 0);
    {
      unsigned long long pj = key2[0][tid ^ 128];
      unsigned long long pj2 = key2[0][tid ^ 64];
      unsigned long long pjj = key2[0][tid ^ 192];
      r0k = SEL(SEL(r0k, pj, kmJ), SEL(pj2, pjj, kmJ), kmJ2);
    }
    {
      unsigned long long pj = key2[1][tid ^ 128];
      unsigned long long pj2 = key2[1][tid ^ 64];
      unsigned long long pjj = key2[1][tid ^ 192];
      r1k = SEL(SEL(r1k, pj, kmJ), SEL(pj2, pjj, kmJ), kmJ2);
    }
    shfl_tail(true);
  }

  // ---- Phase 3: outputs + LDS node map (no barrier needed: lmap/klist
  // disjoint from key2; pre-phase-4 barrier guards the reads) ----
  const double norm = norm_s;
#pragma unroll
  for (int s = 0; s < EPT; ++s) {
    const unsigned long long key = (s == 0) ? r0k : r1k;
    const int pos = tid * EPT + s;
    const int idx = (int)(key & 2047ULL);
    if (pos < KSEL) {
      // recover dot from key (low 11 mantissa bits lost: rel err ~2^-41)
      unsigned long long desc = key & ~2047ULL;
      unsigned long long asc = ~desc;
      unsigned long long u = (asc & 0x8000000000000000ULL)
                                 ? (asc ^ 0x8000000000000000ULL)
                                 : ~asc;
      const double dot = __longlong_as_double((long long)u);
      const float sc = tanhf((float)(dot / norm));
      const int nid = b * KSEL + pos;
      out_batch[nid] = (float)b;
      out_perm[nid] = (float)(base + idx);
      out_score[nid] = sc;
      klist[pos] = idx;
      kscore[pos] = sc;
      lmap[idx] = nid;
    } else {
      lmap[idx] = -1;
    }
  }
  __syncthreads();

  // ---- Phase 4: gather x_out = x[perm] * score (64 rows / iter) ----
  const float4* xg = (const float4*)x;
  float4* xo = (float4*)out_x;
#pragma unroll 4
  for (int rr = 0; rr < KSEL; rr += 64) {
    const int row = rr + rowg;
    const int idx = klist[row];
    const float sc = kscore[row];
    float4 v = xg[(size_t)(base + idx) * 16 + lane];
    v.x *= sc; v.y *= sc; v.z *= sc; v.w *= sc;
    xo[(size_t)(b * KSEL + row) * 16 + lane] = v;
  }

  // ---- Phase 5: edge remap through LDS lmap ----
  const int nE4 = N_PER * DEG / 4;  // 8192 int4 per row of edge_index
  const int4* s_ei = (const int4*)ei + (size_t)b * nE4;
  const int4* d_ei = (const int4*)(ei + (size_t)ETOT) + (size_t)b * nE4;
  float4* o_s = (float4*)out_edge + (size_t)b * nE4;
  float4* o_d = (float4*)(out_edge + (size_t)ETOT) + (size_t)b * nE4;
#pragma unroll 2
  for (int i = tid; i < nE4; i += T) {
    const int4 s4 = s_ei[i];
    const int4 d4 = d_ei[i];
    const int ns0 = lmap[s4.x - base], ns1 = lmap[s4.y - base];
    const int ns2 = lmap[s4.z - base], ns3 = lmap[s4.w - base];
    const int nd0 = lmap[d4.x - base], nd1 = lmap[d4.y - base];
    const int nd2 = lmap[d4.z - base], nd3 = lmap[d4.w - base];
    float4 os, od;
    const bool k0 = (ns0 >= 0) && (nd0 >= 0);
    const bool k1 = (ns1 >= 0) && (nd1 >= 0);
    const bool k2 = (ns2 >= 0) && (nd2 >= 0);
    const bool k3 = (ns3 >= 0) && (nd3 >= 0);
    os.x = k0 ? (float)ns0 : -1.0f; od.x = k0 ? (float)nd0 : -1.0f;
    os.y = k1 ? (float)ns1 : -1.0f; od.y = k1 ? (float)nd1 : -1.0f;
    os.z = k2 ? (float)ns2 : -1.0f; od.z = k2 ? (float)nd2 : -1.0f;
    os.w = k3 ? (float)ns3 : -1.0f; od.w = k3 ? (float)nd3 : -1.0f;
    o_s[i] = os;
    o_d[i] = od;
  }
}

extern "C" void kernel_launch(void* const* d_in, const int* in_sizes, int n_in,
                              void* d_out, int out_size, void* d_ws,
                              size_t ws_size, hipStream_t stream) {
  const float* x = (const float*)d_in[0];
  const int* ei = (const int*)d_in[1];
  // d_in[2] = batch (implied by construction; unused)
  const float* p = (const float*)d_in[3];

  float* out = (float*)d_out;
  float* out_x = out;                // 33554432
  float* out_edge = out + 33554432;  // 33554432
  float* out_batch = out + 67108864;
  float* out_perm = out + 67633152;
  float* out_score = out + 68157440;

  fused_topk_kernel<<<NB, T, 0, stream>>>(x, p, ei, out_x, out_edge, out_batch,
                                          out_perm, out_score);
}